// Round 1
// baseline (1057.993 us; speedup 1.0000x reference)
//
#include <hip/hip_runtime.h>

// GCN layer SpMM: out[i] = sum_{e: rows[e]==i} vals[e] * embeds[cols[e]]
// N = 100000 nodes, E = 1600000 edges, D = 48 features (fp32).
// Baseline: atomic scatter-add, 12 threads per edge (4 floats each via float4 gather).

#define D_FEAT 48
#define QUADS_PER_EDGE 12  // 48 / 4

__global__ void spmm_atomic_kernel(const int* __restrict__ rows,
                                   const int* __restrict__ cols,
                                   const float* __restrict__ vals,
                                   const float* __restrict__ embeds,
                                   float* __restrict__ out,
                                   int n_edges) {
    long long tid = (long long)blockIdx.x * blockDim.x + threadIdx.x;
    long long total = (long long)n_edges * QUADS_PER_EDGE;
    if (tid >= total) return;

    int e = (int)(tid / QUADS_PER_EDGE);
    int q = (int)(tid % QUADS_PER_EDGE);

    int r = rows[e];
    int c = cols[e];
    float v = vals[e];

    // embeds row is 192 B (16 B aligned) -> float4 gather is safe
    const float4* src = reinterpret_cast<const float4*>(embeds + (long long)c * D_FEAT) + q;
    float4 m = *src;

    float* dst = out + (long long)r * D_FEAT + q * 4;
    atomicAdd(dst + 0, v * m.x);
    atomicAdd(dst + 1, v * m.y);
    atomicAdd(dst + 2, v * m.z);
    atomicAdd(dst + 3, v * m.w);
}

extern "C" void kernel_launch(void* const* d_in, const int* in_sizes, int n_in,
                              void* d_out, int out_size, void* d_ws, size_t ws_size,
                              hipStream_t stream) {
    const int*   rows   = (const int*)d_in[0];
    const int*   cols   = (const int*)d_in[1];
    const float* vals   = (const float*)d_in[2];
    const float* embeds = (const float*)d_in[3];
    float*       out    = (float*)d_out;

    int n_edges = in_sizes[0];

    // d_out is poisoned to 0xAA before every timed launch -> must zero it.
    hipMemsetAsync(d_out, 0, (size_t)out_size * sizeof(float), stream);

    long long total_threads = (long long)n_edges * QUADS_PER_EDGE;
    int block = 256;
    long long grid = (total_threads + block - 1) / block;
    spmm_atomic_kernel<<<(int)grid, block, 0, stream>>>(rows, cols, vals, embeds, out, n_edges);
}

// Round 2
// 329.997 us; speedup vs baseline: 3.2061x; 3.2061x over previous
//
#include <hip/hip_runtime.h>

// GCN SpMM, pull-mode with on-device CSR build.
// out[i] = sum_{e: rows[e]==i} vals[e] * embeds[cols[e]]
// N=100000, E=1600000, D=48 (fp32).
//
// Pipeline per launch (all on `stream`, graph-capture safe):
//   0. memsetAsync cnt=0
//   1. hist:      cnt[rows[e]]++                     (int atomics)
//   2. red:       partial[b] = sum of cnt block b
//   3. scanpart:  exclusive scan of partial (1 block)
//   4. scanfinal: off[i] = exclusive prefix; cur[i]=off[i]; off[N]=E
//   5. scatter:   p=cur[r]++; packed[p]=(col,val)    (int atomics, 8B stores)
//   6. pull:      12 lanes/node, lane q owns float4 slice q; register accumulate;
//                 one coalesced 192B store per node. No output atomics.

#define N_NODES 100000
#define D_FEAT 48
#define LANES_PER_NODE 12   // 48 floats / 4 per lane

__global__ void hist_kernel(const int* __restrict__ rows, int* __restrict__ cnt, int n_edges) {
    int e = blockIdx.x * blockDim.x + threadIdx.x;
    if (e < n_edges) atomicAdd(&cnt[rows[e]], 1);
}

__global__ void red_kernel(const int* __restrict__ cnt, int* __restrict__ partial, int n) {
    __shared__ int sm[256];
    int i = blockIdx.x * 256 + threadIdx.x;
    sm[threadIdx.x] = (i < n) ? cnt[i] : 0;
    __syncthreads();
    for (int s = 128; s > 0; s >>= 1) {
        if (threadIdx.x < s) sm[threadIdx.x] += sm[threadIdx.x + s];
        __syncthreads();
    }
    if (threadIdx.x == 0) partial[blockIdx.x] = sm[0];
}

// single block, 512 threads; exclusive scan of partial[nb]
__global__ void scanpart_kernel(int* __restrict__ partial, int nb) {
    __shared__ int sm[512];
    int t = threadIdx.x;
    int v = (t < nb) ? partial[t] : 0;
    sm[t] = v;
    __syncthreads();
    // Hillis-Steele inclusive
    for (int s = 1; s < 512; s <<= 1) {
        int add = (t >= s) ? sm[t - s] : 0;
        __syncthreads();
        sm[t] += add;
        __syncthreads();
    }
    if (t < nb) partial[t] = sm[t] - v;  // exclusive
}

__global__ void scanfinal_kernel(const int* __restrict__ cnt, const int* __restrict__ partial,
                                 int* __restrict__ off, int* __restrict__ cur,
                                 int n, int n_edges) {
    __shared__ int sm[256];
    int t = threadIdx.x;
    int i = blockIdx.x * 256 + t;
    int c = (i < n) ? cnt[i] : 0;
    sm[t] = c;
    __syncthreads();
    for (int s = 1; s < 256; s <<= 1) {
        int add = (t >= s) ? sm[t - s] : 0;
        __syncthreads();
        sm[t] += add;
        __syncthreads();
    }
    if (i < n) {
        int o = partial[blockIdx.x] + sm[t] - c;  // exclusive
        off[i] = o;
        cur[i] = o;
    }
    if (i == 0) off[n] = n_edges;
}

__global__ void scatter_kernel(const int* __restrict__ rows, const int* __restrict__ cols,
                               const float* __restrict__ vals, int* __restrict__ cur,
                               float2* __restrict__ packed, int n_edges) {
    int e = blockIdx.x * blockDim.x + threadIdx.x;
    if (e >= n_edges) return;
    int r = rows[e];
    int p = atomicAdd(&cur[r], 1);
    float2 pk;
    pk.x = __int_as_float(cols[e]);
    pk.y = vals[e];
    packed[p] = pk;
}

__global__ void pull_kernel(const int* __restrict__ off, const float2* __restrict__ packed,
                            const float* __restrict__ embeds, float* __restrict__ out) {
    int tid = blockIdx.x * blockDim.x + threadIdx.x;
    int node = tid / LANES_PER_NODE;
    int q = tid % LANES_PER_NODE;
    if (node >= N_NODES) return;

    int beg = off[node];
    int end = off[node + 1];

    float4 acc = make_float4(0.f, 0.f, 0.f, 0.f);
    for (int e = beg; e < end; ++e) {
        float2 pk = packed[e];            // 12 lanes same addr -> broadcast
        int   c = __float_as_int(pk.x);
        float v = pk.y;
        const float4* src = reinterpret_cast<const float4*>(embeds + (long long)c * D_FEAT) + q;
        float4 m = *src;                  // lanes 0..11 cover 192B contiguous
        acc.x += v * m.x;
        acc.y += v * m.y;
        acc.z += v * m.z;
        acc.w += v * m.w;
    }
    float4* dst = reinterpret_cast<float4*>(out + (long long)node * D_FEAT) + q;
    *dst = acc;
}

extern "C" void kernel_launch(void* const* d_in, const int* in_sizes, int n_in,
                              void* d_out, int out_size, void* d_ws, size_t ws_size,
                              hipStream_t stream) {
    const int*   rows   = (const int*)d_in[0];
    const int*   cols   = (const int*)d_in[1];
    const float* vals   = (const float*)d_in[2];
    const float* embeds = (const float*)d_in[3];
    float*       out    = (float*)d_out;
    int n_edges = in_sizes[0];

    const int N = N_NODES;
    const int NB = (N + 255) / 256;  // 391

    // workspace layout (16B aligned chunks)
    char* ws = (char*)d_ws;
    int*    cnt     = (int*)(ws);                         // N ints      = 400000 B
    int*    off     = (int*)(ws + 400000);                // N+1 ints    = 400016 B
    int*    cur     = (int*)(ws + 800016);                // N ints      = 400000 B
    int*    partial = (int*)(ws + 1200016);               // NB ints
    float2* packed  = (float2*)(ws + 1201584);            // E float2    = 12.8 MB
    // total ~14.0 MB

    hipMemsetAsync(cnt, 0, (size_t)N * sizeof(int), stream);

    int eb = (n_edges + 255) / 256;
    hist_kernel<<<eb, 256, 0, stream>>>(rows, cnt, n_edges);
    red_kernel<<<NB, 256, 0, stream>>>(cnt, partial, N);
    scanpart_kernel<<<1, 512, 0, stream>>>(partial, NB);
    scanfinal_kernel<<<NB, 256, 0, stream>>>(cnt, partial, off, cur, N, n_edges);
    scatter_kernel<<<eb, 256, 0, stream>>>(rows, cols, vals, cur, packed, n_edges);

    long long pull_threads = (long long)N * LANES_PER_NODE;
    int pb = (int)((pull_threads + 255) / 256);
    pull_kernel<<<pb, 256, 0, stream>>>(off, packed, embeds, out);
}